// Round 6
// baseline (251.609 us; speedup 1.0000x reference)
//
#include <hip/hip_runtime.h>
#include <hip/hip_bf16.h>

typedef unsigned short u16;
typedef __attribute__((ext_vector_type(4))) float f32x4;
typedef __attribute__((ext_vector_type(8))) short short8;

#define BN_EPS 1e-5f

__device__ __forceinline__ u16 f2b(float x) {
  union { float f; unsigned int u; } v; v.f = x;
  unsigned int r = (v.u + 0x7FFFu + ((v.u >> 16) & 1u)) >> 16;
  return (u16)r;
}
__device__ __forceinline__ float b2f(u16 u) {
  union { unsigned int u; float f; } v; v.u = ((unsigned int)u) << 16;
  return v.f;
}

// ---------------------------------------------------------------------------
// prep: fold BN into alpha/beta; convert W1/W2 to bf16 in blocked [kt][o][32k]
// ---------------------------------------------------------------------------
__global__ void prep_kernel(const float* __restrict__ w1, const float* __restrict__ b1,
                            const float* __restrict__ g1, const float* __restrict__ be1,
                            const float* __restrict__ m1, const float* __restrict__ v1,
                            const float* __restrict__ w2, const float* __restrict__ b2,
                            const float* __restrict__ g2, const float* __restrict__ be2,
                            const float* __restrict__ m2, const float* __restrict__ v2,
                            u16* __restrict__ w1b, u16* __restrict__ w2b,
                            float* __restrict__ al1, float* __restrict__ bt1,
                            float* __restrict__ al2, float* __restrict__ bt2) {
  int t = threadIdx.x;
  int blk = blockIdx.x;
  if (blk < 384) {                       // w1: 256x384
    int id = blk * 256 + t;
    unsigned o = (unsigned)id / 384u;
    unsigned c = (unsigned)id % 384u;
    w1b[(c >> 5) * 8192 + o * 32 + (c & 31)] = f2b(w1[id]);
  } else if (blk < 640) {                // w2: 256x256
    int j = (blk - 384) * 256 + t;
    unsigned o = (unsigned)j >> 8;
    unsigned c = (unsigned)j & 255u;
    w2b[(c >> 5) * 8192 + o * 32 + (c & 31)] = f2b(w2[j]);
  } else if (blk == 640) {
    float a = g1[t] / sqrtf(v1[t] + BN_EPS);
    al1[t] = a;
    bt1[t] = (b1[t] - m1[t]) * a + be1[t];
  } else {
    float a = g2[t] / sqrtf(v2[t] + BN_EPS);
    al2[t] = a;
    bt2[t] = (b2[t] - m2[t]) * a + be2[t];
  }
}

// ---------------------------------------------------------------------------
// transpose features2 [B][256][2048] f32 -> f2t [B][2048][256] bf16
// ---------------------------------------------------------------------------
__global__ void transpose_f2_kernel(const float* __restrict__ f2, u16* __restrict__ f2t) {
  __shared__ float tile[32][33];
  int t = threadIdx.x;
  int tx = t & 31, ty = t >> 5;          // ty in [0,8)
  int b = blockIdx.z;
  int n2t = blockIdx.x * 32, ct = blockIdx.y * 32;
#pragma unroll
  for (int i = 0; i < 4; ++i) {
    int c = ct + ty + i * 8;
    tile[ty + i * 8][tx] = f2[((size_t)b * 256 + c) * 2048 + n2t + tx];
  }
  __syncthreads();
#pragma unroll
  for (int i = 0; i < 4; ++i) {
    int n2 = n2t + ty + i * 8;
    f2t[((size_t)b * 2048 + n2) * 256 + ct + tx] = f2b(tile[tx][ty + i * 8]);
  }
}

// ---------------------------------------------------------------------------
// knn + interp + skip-copy — round-2 structure (best measured: 86 us) with
// med3-based top-3 distance updates (1 instr each; selection results are
// bit-identical to the cndmask form since d0<=d1<=d2 invariant holds).
// lane = query (p=t&63), wave = slice (s=t>>6): all 64 lanes read the SAME
// pts[j] -> LDS broadcast, conflict-free.
// xb blocked layout: [panel][kt(12)][n(64)][kc(32)] bf16, panel = bn/64.
// ---------------------------------------------------------------------------
__global__ __launch_bounds__(256) void knn_interp_kernel(
    const float* __restrict__ xyz1, const float* __restrict__ xyz2,
    const float* __restrict__ f1, const u16* __restrict__ f2t,
    u16* __restrict__ xb) {
  union Lds {
    struct { float4 pts[2048]; float md[256 * 3]; int mi[256 * 3]; } a;
    float f1t[128 * 65];
  };
  __shared__ Lds lds;
  __shared__ float wts[64 * 3];
  __shared__ int idxs[64 * 3];           // premultiplied by 256

  int t = threadIdx.x;
  int b = blockIdx.x >> 7;
  int n1_0 = (blockIdx.x & 127) * 64;
  int panel = blockIdx.x;                // = b*128 + tile

  // phase 0: stage candidates (x,y,z,|x|^2)
  const float* x2 = xyz2 + b * 3 * 2048;
  for (int j = t; j < 2048; j += 256) {
    float cx = x2[j], cy = x2[2048 + j], cz = x2[4096 + j];
    float nsq = (cx * cx + cy * cy) + cz * cz;
    lds.a.pts[j] = make_float4(cx, cy, cz, nsq);
  }
  __syncthreads();

  // phase 1: sliced top-3; lane = query, wave = slice (broadcast LDS reads)
  {
    int p = t & 63, s = t >> 6;
    int n1 = n1_0 + p;
    const float* x1 = xyz1 + b * 3 * 8192;
    float bx = x1[n1], by = x1[8192 + n1], bz = x1[16384 + n1];
    float n1sq = (bx * bx + by * by) + bz * bz;
    float nx = -2.f * bx, ny = -2.f * by, nz = -2.f * bz;
    float d0 = 3.4e38f, d1 = 3.4e38f, d2 = 3.4e38f;
    int i0 = 0, i1 = 0, i2 = 0;
    int jb = s * 512;
#pragma unroll 4
    for (int jj = 0; jj < 512; ++jj) {
      float4 c = lds.a.pts[jb + jj];
      float sq = fmaf(nx, c.x, fmaf(ny, c.y, fmaf(nz, c.z, n1sq + c.w)));
      int j = jb + jj;
      bool c0 = sq < d0, c1 = sq < d1, c2 = sq < d2;
      i2 = c1 ? i1 : (c2 ? j : i2);
      i1 = c0 ? i0 : (c1 ? j : i1);
      i0 = c0 ? j : i0;
      d2 = __builtin_amdgcn_fmed3f(sq, d1, d2);
      d1 = __builtin_amdgcn_fmed3f(sq, d0, d1);
      d0 = fminf(sq, d0);
    }
    lds.a.md[t * 3 + 0] = d0; lds.a.md[t * 3 + 1] = d1; lds.a.md[t * 3 + 2] = d2;
    lds.a.mi[t * 3 + 0] = i0; lds.a.mi[t * 3 + 1] = i1; lds.a.mi[t * 3 + 2] = i2;
  }
  __syncthreads();
  if (t < 64) {
    // merge slices s=0..3 in ascending-index order (preserves tie-break)
    float d0 = 3.4e38f, d1 = 3.4e38f, d2 = 3.4e38f;
    int i0 = 0, i1 = 0, i2 = 0;
#pragma unroll
    for (int s = 0; s < 4; ++s) {
#pragma unroll
      for (int k = 0; k < 3; ++k) {
        float d = lds.a.md[(s * 64 + t) * 3 + k];
        int i = lds.a.mi[(s * 64 + t) * 3 + k];
        bool c0 = d < d0, c1 = d < d1, c2 = d < d2;
        i2 = c1 ? i1 : (c2 ? i : i2);
        i1 = c0 ? i0 : (c1 ? i : i1);
        i0 = c0 ? i : i0;
        d2 = c1 ? d1 : (c2 ? d : d2);
        d1 = c0 ? d0 : (c1 ? d : d1);
        d0 = c0 ? d : d0;
      }
    }
    float e0 = fmaxf(d0, 1e-10f), e1 = fmaxf(d1, 1e-10f), e2 = fmaxf(d2, 1e-10f);
    float w0 = 1.0f / e0, w1 = 1.0f / e1, w2 = 1.0f / e2;
    float sm = (w0 + w1) + w2;
    wts[t * 3 + 0] = w0 / sm; wts[t * 3 + 1] = w1 / sm; wts[t * 3 + 2] = w2 / sm;
    idxs[t * 3 + 0] = i0 * 256; idxs[t * 3 + 1] = i1 * 256; idxs[t * 3 + 2] = i2 * 256;
  }
  __syncthreads();

  // phase 2: interp 256 channels (thread = channel), write xb blocked
  {
    const u16* f2tb = f2t + (size_t)b * 2048 * 256;
    size_t xbase = (size_t)panel * 24576 + (size_t)((t >> 5) * 2048) + (t & 31);
#pragma unroll 4
    for (int p = 0; p < 64; ++p) {
      int j0 = idxs[p * 3 + 0], j1 = idxs[p * 3 + 1], j2 = idxs[p * 3 + 2];
      float w0 = wts[p * 3 + 0], w1 = wts[p * 3 + 1], w2 = wts[p * 3 + 2];
      float v = (w0 * b2f(f2tb[j0 + t]) + w1 * b2f(f2tb[j1 + t]))
                + w2 * b2f(f2tb[j2 + t]);
      xb[xbase + p * 32] = f2b(v);
    }
  }
  __syncthreads();   // before aliasing lds.a with lds.f1t

  // phase 3: skip features (channels 256..383) via LDS transpose
  {
    const float* f1b = f1 + (size_t)b * 128 * 8192 + n1_0;
    for (int it = 0; it < 32; ++it) {
      int c = it * 4 + (t >> 6);
      int n = t & 63;
      lds.f1t[c * 65 + n] = f1b[(size_t)c * 8192 + n];
    }
    __syncthreads();
    for (int it = 0; it < 32; ++it) {
      int v = it * 256 + t;
      int c = v & 127, p = v >> 7;
      float val = lds.f1t[c * 65 + p];
      xb[(size_t)panel * 24576 + (size_t)(8 + (c >> 5)) * 2048 + p * 32 + (c & 31)] = f2b(val);
    }
  }
}

// ---------------------------------------------------------------------------
// FUSED 2-layer GEMM, occupancy-first variant. 512 threads = 8 waves; each
// wave computes a 64(o) x 32(n) tile (acc = 32 VGPR, half of before), so
// wo = w&3 picks the o-quarter, wn = w>>2 picks the n-half of the 256x64
// panel. __launch_bounds__(512,4) caps VGPR at 128 -> 4 waves/SIMD
// (16 waves/CU), double the latency-hiding of the 64x64-tile version that
// was pinned at ~85 us across r2-r5 regardless of pipelining.
// Layer 1: A=w1b (global), B=xb[panel] (global) -> y1 tile in LDS
//          (blocked [kt2(8)][64n][stride 40] bf16, 40 KB).
// Layer 2: A=w2b (global), B=y1 tile (LDS) -> BN+ReLU -> f32 out.
// ---------------------------------------------------------------------------
__global__ __launch_bounds__(512, 4) void gemm_fused_kernel(
    const u16* __restrict__ xin, const u16* __restrict__ w1b,
    const u16* __restrict__ w2b,
    const float* __restrict__ al1, const float* __restrict__ bt1,
    const float* __restrict__ al2, const float* __restrict__ bt2,
    float* __restrict__ fout) {
  __shared__ u16 y1t[8 * 64 * 40];       // 40960 B
  int t = threadIdx.x;
  int panel = blockIdx.x;
  int w = t >> 6, lane = t & 63, l15 = lane & 15, quad = lane >> 4;
  int wo = w & 3, wn = w >> 2;           // o-quarter, n-half

  f32x4 acc[4][2];
#pragma unroll
  for (int m = 0; m < 4; ++m)
#pragma unroll
    for (int n = 0; n < 2; ++n)
      acc[m][n] = (f32x4){0.f, 0.f, 0.f, 0.f};

  // ---- layer 1 K-loop (KT=12) ----
  {
    const u16* aw = w1b + (size_t)(wo * 64 + l15) * 32 + quad * 8;
    const u16* bx = xin + (size_t)panel * (12 * 2048) +
                    (size_t)(wn * 32 + l15) * 32 + quad * 8;
#pragma unroll 2
    for (int kt = 0; kt < 12; ++kt) {
      short8 af[4], bf[2];
#pragma unroll
      for (int m = 0; m < 4; ++m)
        af[m] = *(const short8*)(aw + kt * 8192 + m * 512);
#pragma unroll
      for (int n = 0; n < 2; ++n)
        bf[n] = *(const short8*)(bx + kt * 2048 + n * 512);
#pragma unroll
      for (int m = 0; m < 4; ++m)
#pragma unroll
        for (int n = 0; n < 2; ++n)
          acc[m][n] = __builtin_amdgcn_mfma_f32_16x16x32_bf16(af[m], bf[n], acc[m][n], 0, 0, 0);
    }
  }

  // ---- epilogue 1: BN+ReLU -> bf16 -> LDS y1 tile (blocked, stride 40) ----
  {
    float al[4][4], bt[4][4];
#pragma unroll
    for (int m = 0; m < 4; ++m)
#pragma unroll
      for (int r = 0; r < 4; ++r) {
        int o = wo * 64 + m * 16 + quad * 4 + r;
        al[m][r] = al1[o];
        bt[m][r] = bt1[o];
      }
#pragma unroll
    for (int m = 0; m < 4; ++m) {
      int kt2 = wo * 2 + (m >> 1);
      int osub = (m & 1) * 16 + quad * 4;
#pragma unroll
      for (int n = 0; n < 2; ++n) {
        int col = wn * 32 + n * 16 + l15;
        ushort4 pk;
        pk.x = f2b(fmaxf(fmaf(al[m][0], acc[m][n][0], bt[m][0]), 0.f));
        pk.y = f2b(fmaxf(fmaf(al[m][1], acc[m][n][1], bt[m][1]), 0.f));
        pk.z = f2b(fmaxf(fmaf(al[m][2], acc[m][n][2], bt[m][2]), 0.f));
        pk.w = f2b(fmaxf(fmaf(al[m][3], acc[m][n][3], bt[m][3]), 0.f));
        *(ushort4*)&y1t[(kt2 * 64 + col) * 40 + osub] = pk;
      }
    }
  }
  __syncthreads();

  // ---- layer 2 K-loop (KT=8): A global, B from LDS ----
#pragma unroll
  for (int m = 0; m < 4; ++m)
#pragma unroll
    for (int n = 0; n < 2; ++n)
      acc[m][n] = (f32x4){0.f, 0.f, 0.f, 0.f};
  {
    const u16* aw = w2b + (size_t)(wo * 64 + l15) * 32 + quad * 8;
#pragma unroll 2
    for (int kt = 0; kt < 8; ++kt) {
      short8 af[4], bf[2];
#pragma unroll
      for (int m = 0; m < 4; ++m)
        af[m] = *(const short8*)(aw + kt * 8192 + m * 512);
#pragma unroll
      for (int n = 0; n < 2; ++n)
        bf[n] = *(const short8*)&y1t[(kt * 64 + wn * 32 + n * 16 + l15) * 40 + quad * 8];
#pragma unroll
      for (int m = 0; m < 4; ++m)
#pragma unroll
        for (int n = 0; n < 2; ++n)
          acc[m][n] = __builtin_amdgcn_mfma_f32_16x16x32_bf16(af[m], bf[n], acc[m][n], 0, 0, 0);
    }
  }

  // ---- epilogue 2: BN+ReLU -> f32 out [b][256][8192] ----
  {
    float al[4][4], bt[4][4];
#pragma unroll
    for (int m = 0; m < 4; ++m)
#pragma unroll
      for (int r = 0; r < 4; ++r) {
        int o = wo * 64 + m * 16 + quad * 4 + r;
        al[m][r] = al2[o];
        bt[m][r] = bt2[o];
      }
    int bb = panel >> 7;
    int n1base = (panel & 127) * 64;
#pragma unroll
    for (int m = 0; m < 4; ++m)
#pragma unroll
      for (int n = 0; n < 2; ++n) {
        int col = wn * 32 + n * 16 + l15;
#pragma unroll
        for (int r = 0; r < 4; ++r) {
          int o = wo * 64 + m * 16 + quad * 4 + r;
          float vv = fmaxf(fmaf(al[m][r], acc[m][n][r], bt[m][r]), 0.f);
          fout[(size_t)(bb * 256 + o) * 8192 + n1base + col] = vv;
        }
      }
  }
}

// ---------------------------------------------------------------------------
// ws layout (bytes):
//   [0,          50331648)  xb   bf16 [1024 panels][12][64][32]   48 MB
//   [50331648,   58720256)  f2t  bf16 [8][2048][256]               8 MB
//   [83886080,   84082688)  w1b  bf16 blocked
//   [84082688,   84213760)  w2b  bf16 blocked
//   [84213760,   84217856)  al1/bt1/al2/bt2 f32
// ---------------------------------------------------------------------------
extern "C" void kernel_launch(void* const* d_in, const int* in_sizes, int n_in,
                              void* d_out, int out_size, void* d_ws, size_t ws_size,
                              hipStream_t stream) {
  const float* xyz1 = (const float*)d_in[0];
  const float* xyz2 = (const float*)d_in[1];
  const float* f1   = (const float*)d_in[2];
  const float* f2   = (const float*)d_in[3];
  const float* w1   = (const float*)d_in[4];
  const float* b1   = (const float*)d_in[5];
  const float* g1   = (const float*)d_in[6];
  const float* be1  = (const float*)d_in[7];
  const float* m1   = (const float*)d_in[8];
  const float* v1   = (const float*)d_in[9];
  const float* w2   = (const float*)d_in[10];
  const float* b2   = (const float*)d_in[11];
  const float* g2   = (const float*)d_in[12];
  const float* be2  = (const float*)d_in[13];
  const float* m2   = (const float*)d_in[14];
  const float* v2   = (const float*)d_in[15];

  char* ws = (char*)d_ws;
  u16* xb   = (u16*)(ws);
  u16* f2t  = (u16*)(ws + 50331648);
  u16* w1b  = (u16*)(ws + 83886080);
  u16* w2b  = (u16*)(ws + 84082688);
  float* al1 = (float*)(ws + 84213760);
  float* bt1 = (float*)(ws + 84214784);
  float* al2 = (float*)(ws + 84215808);
  float* bt2 = (float*)(ws + 84216832);
  float* out = (float*)d_out;

  prep_kernel<<<642, 256, 0, stream>>>(w1, b1, g1, be1, m1, v1,
                                       w2, b2, g2, be2, m2, v2,
                                       w1b, w2b, al1, bt1, al2, bt2);
  transpose_f2_kernel<<<dim3(64, 8, 8), 256, 0, stream>>>(f2, f2t);
  knn_interp_kernel<<<1024, 256, 0, stream>>>(xyz1, xyz2, f1, f2t, xb);
  gemm_fused_kernel<<<1024, 512, 0, stream>>>(xb, w1b, w2b, al1, bt1, al2, bt2, out);
}

// Round 7
// 240.282 us; speedup vs baseline: 1.0471x; 1.0471x over previous
//
#include <hip/hip_runtime.h>
#include <hip/hip_bf16.h>

typedef unsigned short u16;
typedef __attribute__((ext_vector_type(4))) float f32x4;
typedef __attribute__((ext_vector_type(8))) short short8;

#define BN_EPS 1e-5f

__device__ __forceinline__ u16 f2b(float x) {
  union { float f; unsigned int u; } v; v.f = x;
  unsigned int r = (v.u + 0x7FFFu + ((v.u >> 16) & 1u)) >> 16;
  return (u16)r;
}
__device__ __forceinline__ float b2f(u16 u) {
  union { unsigned int u; float f; } v; v.u = ((unsigned int)u) << 16;
  return v.f;
}

// ---------------------------------------------------------------------------
// merged prep + transpose (one launch):
//  blocks [0,4096):    transpose f2 [B][256][2048] f32 -> f2t [B][2048][256] bf16
//  blocks [4096,4738): fold BN into alpha/beta; W1/W2 -> bf16 blocked [kt][o][32k]
// ---------------------------------------------------------------------------
__global__ void prep_transpose_kernel(
    const float* __restrict__ f2, u16* __restrict__ f2t,
    const float* __restrict__ w1, const float* __restrict__ b1,
    const float* __restrict__ g1, const float* __restrict__ be1,
    const float* __restrict__ m1, const float* __restrict__ v1,
    const float* __restrict__ w2, const float* __restrict__ b2,
    const float* __restrict__ g2, const float* __restrict__ be2,
    const float* __restrict__ m2, const float* __restrict__ v2,
    u16* __restrict__ w1b, u16* __restrict__ w2b,
    float* __restrict__ al1, float* __restrict__ bt1,
    float* __restrict__ al2, float* __restrict__ bt2) {
  __shared__ float tile[32][33];
  int t = threadIdx.x;
  int blk = blockIdx.x;
  if (blk < 4096) {
    int b = blk >> 9, rem = blk & 511;
    int n2t = (rem & 63) * 32, ct = (rem >> 6) * 32;
    int tx = t & 31, ty = t >> 5;
#pragma unroll
    for (int i = 0; i < 4; ++i) {
      int c = ct + ty + i * 8;
      tile[ty + i * 8][tx] = f2[((size_t)b * 256 + c) * 2048 + n2t + tx];
    }
    __syncthreads();
#pragma unroll
    for (int i = 0; i < 4; ++i) {
      int n2 = n2t + ty + i * 8;
      f2t[((size_t)b * 2048 + n2) * 256 + ct + tx] = f2b(tile[tx][ty + i * 8]);
    }
  } else {
    int bb = blk - 4096;
    if (bb < 384) {                      // w1: 256x384
      int id = bb * 256 + t;
      unsigned o = (unsigned)id / 384u;
      unsigned c = (unsigned)id % 384u;
      w1b[(c >> 5) * 8192 + o * 32 + (c & 31)] = f2b(w1[id]);
    } else if (bb < 640) {               // w2: 256x256
      int j = (bb - 384) * 256 + t;
      unsigned o = (unsigned)j >> 8;
      unsigned c = (unsigned)j & 255u;
      w2b[(c >> 5) * 8192 + o * 32 + (c & 31)] = f2b(w2[j]);
    } else if (bb == 640) {
      float a = g1[t] / sqrtf(v1[t] + BN_EPS);
      al1[t] = a;
      bt1[t] = (b1[t] - m1[t]) * a + be1[t];
    } else {
      float a = g2[t] / sqrtf(v2[t] + BN_EPS);
      al2[t] = a;
      bt2[t] = (b2[t] - m2[t]) * a + be2[t];
    }
  }
}

// ---------------------------------------------------------------------------
// FUSED knn + interp + 2-layer GEMM. One block = one panel (batch b, 64
// query points). The interp activations (channels 0..255, kt 0..7) never
// leave LDS; skip-feature channels (kt 8..11) round-trip a small global
// staging buffer xbs (16 MB instead of r5's 96 MB xb round trip).
//
// LDS map (75264 B total -> 2 blocks/CU), lifetime-disjoint regions:
//   [0,     40960)  R1: ph0/1: pts f32x4[2048] (32768) + md f32[768]@32768
//                       + mi i32[768]@35840 | ph3: f1t f32[128*65] (33280)
//                       | gemm: y1t u16[8*64*40] (stride-40 r5 layout)
//   [40960, 73728)  xbt u16[8][64][32] — layer-1 B tile, kt 0..7
//   [73728, 74496)  wts f32[192]
//   [74496, 75264)  idxs i32[192] (premultiplied by 256)
// Barriers sit at every region-lifetime transition.
// Phase-1 internals identical to r6 (med3); gemm loops/epilogues identical
// to r5; MFMA K-order unchanged -> bit-identical output vs r5/r6.
// ---------------------------------------------------------------------------
__global__ __launch_bounds__(256) void knn_gemm_kernel(
    const float* __restrict__ xyz1, const float* __restrict__ xyz2,
    const float* __restrict__ f1, const u16* __restrict__ f2t,
    u16* __restrict__ xbs,
    const u16* __restrict__ w1b, const u16* __restrict__ w2b,
    const float* __restrict__ al1, const float* __restrict__ bt1,
    const float* __restrict__ al2, const float* __restrict__ bt2,
    float* __restrict__ fout) {
  __shared__ __align__(16) char raw[75264];
  float4* pts = (float4*)raw;
  float*  md  = (float*)(raw + 32768);
  int*    mi  = (int*)(raw + 35840);
  float*  f1t = (float*)raw;
  u16*    y1t = (u16*)raw;
  u16*    xbt = (u16*)(raw + 40960);
  float*  wts = (float*)(raw + 73728);
  int*    idxs = (int*)(raw + 74496);

  int t = threadIdx.x;
  int panel = blockIdx.x;
  int b = panel >> 7;
  int n1_0 = (panel & 127) * 64;

  // ---- phase 0: stage candidates (x,y,z,|x|^2) ----
  const float* x2 = xyz2 + b * 3 * 2048;
  for (int j = t; j < 2048; j += 256) {
    float cx = x2[j], cy = x2[2048 + j], cz = x2[4096 + j];
    float nsq = (cx * cx + cy * cy) + cz * cz;
    pts[j] = make_float4(cx, cy, cz, nsq);
  }
  __syncthreads();

  // ---- phase 1: sliced top-3; lane = query, wave = slice (broadcast) ----
  {
    int p = t & 63, s = t >> 6;
    int n1 = n1_0 + p;
    const float* x1 = xyz1 + b * 3 * 8192;
    float bx = x1[n1], by = x1[8192 + n1], bz = x1[16384 + n1];
    float n1sq = (bx * bx + by * by) + bz * bz;
    float nx = -2.f * bx, ny = -2.f * by, nz = -2.f * bz;
    float d0 = 3.4e38f, d1 = 3.4e38f, d2 = 3.4e38f;
    int i0 = 0, i1 = 0, i2 = 0;
    int jb = s * 512;
#pragma unroll 4
    for (int jj = 0; jj < 512; ++jj) {
      float4 c = pts[jb + jj];
      float sq = fmaf(nx, c.x, fmaf(ny, c.y, fmaf(nz, c.z, n1sq + c.w)));
      int j = jb + jj;
      bool c0 = sq < d0, c1 = sq < d1, c2 = sq < d2;
      i2 = c1 ? i1 : (c2 ? j : i2);
      i1 = c0 ? i0 : (c1 ? j : i1);
      i0 = c0 ? j : i0;
      d2 = __builtin_amdgcn_fmed3f(sq, d1, d2);
      d1 = __builtin_amdgcn_fmed3f(sq, d0, d1);
      d0 = fminf(sq, d0);
    }
    md[t * 3 + 0] = d0; md[t * 3 + 1] = d1; md[t * 3 + 2] = d2;
    mi[t * 3 + 0] = i0; mi[t * 3 + 1] = i1; mi[t * 3 + 2] = i2;
  }
  __syncthreads();
  if (t < 64) {
    // merge slices s=0..3 in ascending-index order (preserves tie-break)
    float d0 = 3.4e38f, d1 = 3.4e38f, d2 = 3.4e38f;
    int i0 = 0, i1 = 0, i2 = 0;
#pragma unroll
    for (int s = 0; s < 4; ++s) {
#pragma unroll
      for (int k = 0; k < 3; ++k) {
        float d = md[(s * 64 + t) * 3 + k];
        int i = mi[(s * 64 + t) * 3 + k];
        bool c0 = d < d0, c1 = d < d1, c2 = d < d2;
        i2 = c1 ? i1 : (c2 ? i : i2);
        i1 = c0 ? i0 : (c1 ? i : i1);
        i0 = c0 ? i : i0;
        d2 = c1 ? d1 : (c2 ? d : d2);
        d1 = c0 ? d0 : (c1 ? d : d1);
        d0 = c0 ? d : d0;
      }
    }
    float e0 = fmaxf(d0, 1e-10f), e1 = fmaxf(d1, 1e-10f), e2 = fmaxf(d2, 1e-10f);
    float w0 = 1.0f / e0, w1 = 1.0f / e1, w2 = 1.0f / e2;
    float sm = (w0 + w1) + w2;
    wts[t * 3 + 0] = w0 / sm; wts[t * 3 + 1] = w1 / sm; wts[t * 3 + 2] = w2 / sm;
    idxs[t * 3 + 0] = i0 * 256; idxs[t * 3 + 1] = i1 * 256; idxs[t * 3 + 2] = i2 * 256;
  }
  __syncthreads();     // md/mi + pts dead past here

  // ---- phase 2: interp 256 channels (thread = channel) -> LDS B-tile ----
  {
    const u16* f2tb = f2t + (size_t)b * 2048 * 256;
    int xbase = (t >> 5) * 2048 + (t & 31);
#pragma unroll 4
    for (int p = 0; p < 64; ++p) {
      int j0 = idxs[p * 3 + 0], j1 = idxs[p * 3 + 1], j2 = idxs[p * 3 + 2];
      float w0 = wts[p * 3 + 0], w1 = wts[p * 3 + 1], w2 = wts[p * 3 + 2];
      float v = (w0 * b2f(f2tb[j0 + t]) + w1 * b2f(f2tb[j1 + t]))
                + w2 * b2f(f2tb[j2 + t]);
      xbt[xbase + p * 32] = f2b(v);
    }
  }

  // ---- phase 3: skip features via f1t transpose -> global xbs (kt 8..11) ----
  {
    const float* f1b = f1 + (size_t)b * 128 * 8192 + n1_0;
    for (int it = 0; it < 32; ++it) {
      int c = it * 4 + (t >> 6);
      int n = t & 63;
      f1t[c * 65 + n] = f1b[(size_t)c * 8192 + n];
    }
    __syncthreads();
    u16* xso = xbs + (size_t)panel * 8192;
    for (int it = 0; it < 32; ++it) {
      int v = it * 256 + t;
      int c = v & 127, p = v >> 7;
      xso[(c >> 5) * 2048 + p * 32 + (c & 31)] = f2b(f1t[c * 65 + p]);
    }
  }
  __syncthreads();     // xbt complete; f1t dead; xbs drained (barrier waits vmcnt)

  // ================= fused 2-layer GEMM (r5 structure) =================
  int w = t >> 6, lane = t & 63, l15 = lane & 15, quad = lane >> 4;

  f32x4 acc[4][4];
#pragma unroll
  for (int m = 0; m < 4; ++m)
#pragma unroll
    for (int n = 0; n < 4; ++n)
      acc[m][n] = (f32x4){0.f, 0.f, 0.f, 0.f};

  // ---- layer 1: kt 0..7 B from LDS, kt 8..11 B from global xbs ----
  {
    const u16* aw = w1b + (size_t)(w * 64 + l15) * 32 + quad * 8;
    const u16* bxs = xbs + (size_t)panel * 8192 + (size_t)l15 * 32 + quad * 8;
#pragma unroll 2
    for (int kt = 0; kt < 8; ++kt) {
      short8 af[4], bf[4];
#pragma unroll
      for (int m = 0; m < 4; ++m)
        af[m] = *(const short8*)(aw + kt * 8192 + m * 512);
#pragma unroll
      for (int n = 0; n < 4; ++n)
        bf[n] = *(const short8*)&xbt[kt * 2048 + (n * 16 + l15) * 32 + quad * 8];
#pragma unroll
      for (int m = 0; m < 4; ++m)
#pragma unroll
        for (int n = 0; n < 4; ++n)
          acc[m][n] = __builtin_amdgcn_mfma_f32_16x16x32_bf16(af[m], bf[n], acc[m][n], 0, 0, 0);
    }
#pragma unroll 2
    for (int kt = 0; kt < 4; ++kt) {
      short8 af[4], bf[4];
#pragma unroll
      for (int m = 0; m < 4; ++m)
        af[m] = *(const short8*)(aw + (8 + kt) * 8192 + m * 512);
#pragma unroll
      for (int n = 0; n < 4; ++n)
        bf[n] = *(const short8*)(bxs + kt * 2048 + n * 512);
#pragma unroll
      for (int m = 0; m < 4; ++m)
#pragma unroll
        for (int n = 0; n < 4; ++n)
          acc[m][n] = __builtin_amdgcn_mfma_f32_16x16x32_bf16(af[m], bf[n], acc[m][n], 0, 0, 0);
    }
  }

  // ---- epilogue 1: BN+ReLU -> bf16 -> y1t (stride-40, aliases R1) ----
  {
    float al[4][4], bt[4][4];
#pragma unroll
    for (int m = 0; m < 4; ++m)
#pragma unroll
      for (int r = 0; r < 4; ++r) {
        int o = w * 64 + m * 16 + quad * 4 + r;
        al[m][r] = al1[o];
        bt[m][r] = bt1[o];
      }
#pragma unroll
    for (int m = 0; m < 4; ++m) {
      int kt2 = w * 2 + (m >> 1);
      int osub = (m & 1) * 16 + quad * 4;
#pragma unroll
      for (int n = 0; n < 4; ++n) {
        int col = n * 16 + l15;
        ushort4 pk;
        pk.x = f2b(fmaxf(fmaf(al[m][0], acc[m][n][0], bt[m][0]), 0.f));
        pk.y = f2b(fmaxf(fmaf(al[m][1], acc[m][n][1], bt[m][1]), 0.f));
        pk.z = f2b(fmaxf(fmaf(al[m][2], acc[m][n][2], bt[m][2]), 0.f));
        pk.w = f2b(fmaxf(fmaf(al[m][3], acc[m][n][3], bt[m][3]), 0.f));
        *(ushort4*)&y1t[(kt2 * 64 + col) * 40 + osub] = pk;
      }
    }
  }
  __syncthreads();

  // ---- layer 2 (KT=8): A global, B from y1t LDS ----
#pragma unroll
  for (int m = 0; m < 4; ++m)
#pragma unroll
    for (int n = 0; n < 4; ++n)
      acc[m][n] = (f32x4){0.f, 0.f, 0.f, 0.f};
  {
    const u16* aw = w2b + (size_t)(w * 64 + l15) * 32 + quad * 8;
#pragma unroll 2
    for (int kt = 0; kt < 8; ++kt) {
      short8 af[4], bf[4];
#pragma unroll
      for (int m = 0; m < 4; ++m)
        af[m] = *(const short8*)(aw + kt * 8192 + m * 512);
#pragma unroll
      for (int n = 0; n < 4; ++n)
        bf[n] = *(const short8*)&y1t[(kt * 64 + n * 16 + l15) * 40 + quad * 8];
#pragma unroll
      for (int m = 0; m < 4; ++m)
#pragma unroll
        for (int n = 0; n < 4; ++n)
          acc[m][n] = __builtin_amdgcn_mfma_f32_16x16x32_bf16(af[m], bf[n], acc[m][n], 0, 0, 0);
    }
  }

  // ---- epilogue 2: BN+ReLU -> f32 out [b][256][8192] ----
  {
    float al[4][4], bt[4][4];
#pragma unroll
    for (int m = 0; m < 4; ++m)
#pragma unroll
      for (int r = 0; r < 4; ++r) {
        int o = w * 64 + m * 16 + quad * 4 + r;
        al[m][r] = al2[o];
        bt[m][r] = bt2[o];
      }
    int bb = panel >> 7;
    int n1base = (panel & 127) * 64;
#pragma unroll
    for (int m = 0; m < 4; ++m)
#pragma unroll
      for (int n = 0; n < 4; ++n) {
        int col = n * 16 + l15;
#pragma unroll
        for (int r = 0; r < 4; ++r) {
          int o = w * 64 + m * 16 + quad * 4 + r;
          float vv = fmaxf(fmaf(al[m][r], acc[m][n][r], bt[m][r]), 0.f);
          fout[(size_t)(bb * 256 + o) * 8192 + n1base + col] = vv;
        }
      }
  }
}

// ---------------------------------------------------------------------------
// ws layout (bytes):
//   [0,         16777216)  xbs  bf16 [1024 panels][4 kt][64][32]  16 MB
//   [16777216,  25165824)  f2t  bf16 [8][2048][256]                8 MB
//   [83886080,  84082688)  w1b  bf16 blocked
//   [84082688,  84213760)  w2b  bf16 blocked
//   [84213760,  84217856)  al1/bt1/al2/bt2 f32
// ---------------------------------------------------------------------------
extern "C" void kernel_launch(void* const* d_in, const int* in_sizes, int n_in,
                              void* d_out, int out_size, void* d_ws, size_t ws_size,
                              hipStream_t stream) {
  const float* xyz1 = (const float*)d_in[0];
  const float* xyz2 = (const float*)d_in[1];
  const float* f1   = (const float*)d_in[2];
  const float* f2   = (const float*)d_in[3];
  const float* w1   = (const float*)d_in[4];
  const float* b1   = (const float*)d_in[5];
  const float* g1   = (const float*)d_in[6];
  const float* be1  = (const float*)d_in[7];
  const float* m1   = (const float*)d_in[8];
  const float* v1   = (const float*)d_in[9];
  const float* w2   = (const float*)d_in[10];
  const float* b2   = (const float*)d_in[11];
  const float* g2   = (const float*)d_in[12];
  const float* be2  = (const float*)d_in[13];
  const float* m2   = (const float*)d_in[14];
  const float* v2   = (const float*)d_in[15];

  char* ws = (char*)d_ws;
  u16* xbs  = (u16*)(ws);
  u16* f2t  = (u16*)(ws + 16777216);
  u16* w1b  = (u16*)(ws + 83886080);
  u16* w2b  = (u16*)(ws + 84082688);
  float* al1 = (float*)(ws + 84213760);
  float* bt1 = (float*)(ws + 84214784);
  float* al2 = (float*)(ws + 84215808);
  float* bt2 = (float*)(ws + 84216832);
  float* out = (float*)d_out;

  prep_transpose_kernel<<<4738, 256, 0, stream>>>(
      f2, f2t, w1, b1, g1, be1, m1, v1, w2, b2, g2, be2, m2, v2,
      w1b, w2b, al1, bt1, al2, bt2);
  knn_gemm_kernel<<<1024, 256, 0, stream>>>(
      xyz1, xyz2, f1, f2t, xbs, w1b, w2b, al1, bt1, al2, bt2, out);
}